// Round 8
// baseline (409.840 us; speedup 1.0000x reference)
//
#include <hip/hip_runtime.h>
#include <math.h>

#define BSAMP 4096
#define D_IN  768
#define D_OUT 1024
#define NEXP  10
#define LN_EPS 1e-5f

typedef __attribute__((ext_vector_type(8))) short bf16x8;
typedef __attribute__((ext_vector_type(4))) float f32x4;

__device__ __forceinline__ unsigned short f2b(float f) {
    union { float f; unsigned int i; } v; v.f = f;
    unsigned int x = v.i;
    unsigned int r = (x + 0x7fffu + ((x >> 16) & 1u)) >> 16;   // RNE
    return (unsigned short)r;
}

// ---------------- routing (inputs f32; OUTPUTS f32 — the round-7 fix) ----------------

__global__ void k3_init(int* counts, int* cursor) {
    int t = threadIdx.x;
    if (t < 16) { counts[t] = 0; cursor[t] = 0; }
}

// argmax router; also writes the f32 logits passthrough (region 1), bit-exact
__global__ void k3_router(const float* __restrict__ logits,
                          int* __restrict__ cls, int* __restrict__ counts,
                          float* __restrict__ out1) {
    int b = blockIdx.x * 256 + threadIdx.x;
    if (b >= BSAMP) return;
    const float* L = logits + (size_t)b * NEXP;
    float best = L[0]; int be = 0;
    #pragma unroll
    for (int e = 0; e < NEXP; e++) {
        float v = L[e];
        out1[(size_t)b * NEXP + e] = v;          // f32 bit-exact passthrough
        if (v > best) { best = v; be = e; }      // strict > == first-max (jnp.argmax)
    }
    cls[b] = be;
    atomicAdd(&counts[be], 1);
}

__global__ void k3_scan(const int* counts, int* offs, int* cursor) {
    if (threadIdx.x == 0) {
        int s = 0;
        for (int e = 0; e < NEXP; e++) { offs[e] = s; cursor[e] = s; s += counts[e]; }
        offs[NEXP] = s;
    }
}

__global__ void k3_scatter(const int* __restrict__ cls, int* __restrict__ cursor,
                           int* __restrict__ idx) {
    int b = blockIdx.x * 256 + threadIdx.x;
    if (b >= BSAMP) return;
    int p = atomicAdd(&cursor[cls[b]], 1);
    idx[p] = b;
}

// ---------------- GEMM1: out0[idx[p]][n] = f32( x[idx[p]] @ W1[e] )  (embed1) ----
// Tile 64 rows x 128 cols, BK=32. 256 thr = 4 waves, each 32x64 (2x4 mfma 16x16x32).
__global__ __launch_bounds__(256)
void k3_gemm1(const float* __restrict__ X, const float* __restrict__ W1,
              const int* __restrict__ offs, const int* __restrict__ idx,
              float* __restrict__ out0) {
    const int K = D_IN;
    const int e = blockIdx.z;
    const int rowStart = offs[e] + blockIdx.y * 64;
    const int rowEnd = offs[e + 1];
    if (rowStart >= rowEnd) return;
    const int n0 = blockIdx.x * 128;

    __shared__ __align__(16) unsigned short Alds[64 * 32];
    __shared__ __align__(16) unsigned short Blds[128 * 32];
    __shared__ int rowIdxL[64];

    const int tid  = threadIdx.x;
    const int lane = tid & 63;
    const int wave = tid >> 6;
    const int quad = lane >> 4;
    const int l16  = lane & 15;

    if (tid < 64) {
        int p = rowStart + tid;
        int ps = p < rowEnd ? p : rowEnd - 1;    // clamp; overhang rows not stored
        rowIdxL[tid] = idx[ps];
    }
    __syncthreads();

    const int ar = tid >> 2;                      // 0..63
    const int ak = (tid & 3) * 8;
    const float* aBase = X + (size_t)rowIdxL[ar] * K;

    const int bn  = tid & 127;
    const int bkg = (tid >> 7) * 8;

    f32x4 acc[2][4];
    const f32x4 zf = {0.f, 0.f, 0.f, 0.f};
    #pragma unroll
    for (int r = 0; r < 2; r++)
        #pragma unroll
        for (int c = 0; c < 4; c++) acc[r][c] = zf;

    const int wrow = (wave & 1) * 32;
    const int wcol = (wave >> 1) * 64;

    for (int k0 = 0; k0 < K; k0 += 32) {
        __syncthreads();
        {   // A: f32 -> bf16 -> LDS
            const float* s = aBase + k0 + ak;
            float4 v0 = *(const float4*)s;
            float4 v1 = *(const float4*)(s + 4);
            unsigned short t[8] = { f2b(v0.x), f2b(v0.y), f2b(v0.z), f2b(v0.w),
                                    f2b(v1.x), f2b(v1.y), f2b(v1.z), f2b(v1.w) };
            *(bf16x8*)&Alds[ar * 32 + ak] = *(bf16x8*)t;
        }
        {   // B: transpose-on-stage; thread covers col n0+bn, k {bkg..+7, bkg+16..+23}
            unsigned short tmp[16];
            const float* bsrc = W1 + (size_t)e * K * D_OUT + (size_t)(k0 + bkg) * D_OUT + n0 + bn;
            #pragma unroll
            for (int kh = 0; kh < 2; kh++)
                #pragma unroll
                for (int j = 0; j < 8; j++)
                    tmp[kh * 8 + j] = f2b(bsrc[(size_t)(kh * 16 + j) * D_OUT]);
            #pragma unroll
            for (int kh = 0; kh < 2; kh++)
                *(bf16x8*)&Blds[bn * 32 + bkg + kh * 16] = *(bf16x8*)&tmp[kh * 8];
        }
        __syncthreads();
        bf16x8 a[2], bfr[4];
        #pragma unroll
        for (int r = 0; r < 2; r++)
            a[r] = *(const bf16x8*)&Alds[(wrow + r * 16 + l16) * 32 + quad * 8];
        #pragma unroll
        for (int c = 0; c < 4; c++)
            bfr[c] = *(const bf16x8*)&Blds[(wcol + c * 16 + l16) * 32 + quad * 8];
        #pragma unroll
        for (int r = 0; r < 2; r++)
            #pragma unroll
            for (int c = 0; c < 4; c++)
                acc[r][c] = __builtin_amdgcn_mfma_f32_16x16x32_bf16(a[r], bfr[c], acc[r][c], 0, 0, 0);
    }

    // C/D layout: col = lane&15, row = quad*4 + reg  -> f32 stores to original rows
    #pragma unroll
    for (int r = 0; r < 2; r++)
        #pragma unroll
        for (int c = 0; c < 4; c++)
            #pragma unroll
            for (int q = 0; q < 4; q++) {
                int m = wrow + r * 16 + quad * 4 + q;
                int pp = rowStart + m;
                if (pp < rowEnd) {
                    int n = n0 + wcol + c * 16 + l16;
                    out0[(size_t)rowIdxL[m] * D_OUT + n] = acc[r][c][q];
                }
            }
}

// ---------------- GEMM2 + LN + L2 fused, in place on out0 (f32) ----------------
// Block owns 16 grouped rows (original rows idx[p]); full 1024 cols via 4 passes
// of 256 cols. 256 thr = 4 waves. Reads f32 embed1 from its own rows (gelu at
// stage, raw at epilogue), writes normalized f32 back to the SAME rows =>
// race-free (idx is a permutation). LDS ~17.6 KB.
__global__ __launch_bounds__(256)
void k3_gemm2(const float* __restrict__ W2,
              const float* __restrict__ gam, const float* __restrict__ bet,
              const int* __restrict__ offs, const int* __restrict__ idx,
              float* __restrict__ out0) {
    const int K = D_OUT;
    const int e = blockIdx.z;
    const int rowStart = offs[e] + blockIdx.y * 16;
    const int rowEnd = offs[e + 1];
    if (rowStart >= rowEnd) return;

    __shared__ __align__(16) unsigned short Alds[16 * 32];
    __shared__ __align__(16) unsigned short Blds[256 * 32];
    __shared__ float red[16][4][2];
    __shared__ int rowIdxL[16];

    const int tid  = threadIdx.x;
    const int lane = tid & 63;
    const int wave = tid >> 6;    // 0..3
    const int quad = lane >> 4;
    const int l16  = lane & 15;

    if (tid < 16) {
        int p = rowStart + tid;
        int ps = p < rowEnd ? p : rowEnd - 1;
        rowIdxL[tid] = idx[ps];
    }
    __syncthreads();

    // A staging (tid<64): row tid>>2 (0..15), k (tid&3)*8
    const int asr = (tid & 63) >> 2;
    const int ask = (tid & 3) * 8;
    const size_t aRow = (size_t)rowIdxL[asr] * D_OUT;

    f32x4 acc[16];
    const f32x4 zf = {0.f, 0.f, 0.f, 0.f};
    #pragma unroll
    for (int i = 0; i < 16; i++) acc[i] = zf;

    for (int pass = 0; pass < 4; pass++) {
        for (int k0 = 0; k0 < K; k0 += 32) {
            __syncthreads();
            if (tid < 64) {      // A: gelu(embed1) from out0 f32 (own rows)
                const float* s = out0 + aRow + k0 + ask;
                float4 v0 = *(const float4*)s;
                float4 v1 = *(const float4*)(s + 4);
                float vv[8] = { v0.x, v0.y, v0.z, v0.w, v1.x, v1.y, v1.z, v1.w };
                unsigned short t[8];
                #pragma unroll
                for (int j = 0; j < 8; j++) {
                    float v = vv[j];
                    t[j] = f2b(v / (1.0f + __expf(-1.702f * v)));
                }
                *(bf16x8*)&Alds[asr * 32 + ask] = *(bf16x8*)t;
            }
            {   // B: one col per thread (n = pass*256 + tid), 32 k, transpose
                const int n = pass * 256 + tid;
                const float* bs = W2 + ((size_t)e * K + k0) * D_OUT + n;
                unsigned short tmp[32];
                #pragma unroll
                for (int kk = 0; kk < 32; kk++) tmp[kk] = f2b(bs[(size_t)kk * D_OUT]);
                #pragma unroll
                for (int j = 0; j < 4; j++)
                    *(bf16x8*)&Blds[tid * 32 + j * 8] = *(bf16x8*)&tmp[j * 8];
            }
            __syncthreads();
            bf16x8 a = *(const bf16x8*)&Alds[l16 * 32 + quad * 8];
            #pragma unroll
            for (int c = 0; c < 4; c++) {
                bf16x8 b = *(const bf16x8*)&Blds[(wave * 64 + c * 16 + l16) * 32 + quad * 8];
                acc[pass * 4 + c] = __builtin_amdgcn_mfma_f32_16x16x32_bf16(a, b, acc[pass * 4 + c], 0, 0, 0);
            }
        }
    }
    __syncthreads();

    // acc[i] -> col = (i>>2)*256 + wave*64 + (i&3)*16 + l16 ; row rl = quad*4+q
    float sums[4] = {0.f, 0.f, 0.f, 0.f}, sqs[4] = {0.f, 0.f, 0.f, 0.f};
    #pragma unroll
    for (int q = 0; q < 4; q++) {
        int rl = quad * 4 + q;
        size_t rb = (size_t)rowIdxL[rl] * D_OUT;
        #pragma unroll
        for (int i = 0; i < 16; i++) {
            int col = (i >> 2) * 256 + wave * 64 + (i & 3) * 16 + l16;
            float s = acc[i][q] + out0[rb + col];   // + embed1 (raw f32)
            acc[i][q] = s;
            sums[q] += s; sqs[q] += s * s;
        }
    }
    #pragma unroll
    for (int m = 1; m <= 8; m <<= 1)
        #pragma unroll
        for (int q = 0; q < 4; q++) {
            sums[q] += __shfl_xor(sums[q], m, 64);
            sqs[q]  += __shfl_xor(sqs[q],  m, 64);
        }
    if (l16 == 0)
        #pragma unroll
        for (int q = 0; q < 4; q++) {
            red[quad * 4 + q][wave][0] = sums[q];
            red[quad * 4 + q][wave][1] = sqs[q];
        }
    __syncthreads();   // also orders: embed1 reads above precede writes below
    float mean[4], inv[4];
    #pragma unroll
    for (int q = 0; q < 4; q++) {
        int rl = quad * 4 + q;
        float S = red[rl][0][0] + red[rl][1][0] + red[rl][2][0] + red[rl][3][0];
        float Q = red[rl][0][1] + red[rl][1][1] + red[rl][2][1] + red[rl][3][1];
        mean[q] = S * (1.0f / 1024.0f);
        float var = Q * (1.0f / 1024.0f) - mean[q] * mean[q];
        inv[q] = rsqrtf(var + LN_EPS);
    }
    __syncthreads();

    float gv[16], bv[16];
    #pragma unroll
    for (int i = 0; i < 16; i++) {
        int col = (i >> 2) * 256 + wave * 64 + (i & 3) * 16 + l16;
        gv[i] = gam[(size_t)e * D_OUT + col];
        bv[i] = bet[(size_t)e * D_OUT + col];
    }

    float y2[4] = {0.f, 0.f, 0.f, 0.f};
    #pragma unroll
    for (int q = 0; q < 4; q++)
        #pragma unroll
        for (int i = 0; i < 16; i++) {
            float y = (acc[i][q] - mean[q]) * inv[q] * gv[i] + bv[i];
            acc[i][q] = y;
            y2[q] += y * y;
        }
    #pragma unroll
    for (int m = 1; m <= 8; m <<= 1)
        #pragma unroll
        for (int q = 0; q < 4; q++) y2[q] += __shfl_xor(y2[q], m, 64);
    if (l16 == 0)
        #pragma unroll
        for (int q = 0; q < 4; q++) red[quad * 4 + q][wave][0] = y2[q];
    __syncthreads();
    #pragma unroll
    for (int q = 0; q < 4; q++) {
        int rl = quad * 4 + q;
        int prow = rowStart + rl;
        if (prow < rowEnd) {
            float rn = rsqrtf(red[rl][0][0] + red[rl][1][0] + red[rl][2][0] + red[rl][3][0]);
            size_t rb = (size_t)rowIdxL[rl] * D_OUT;   // same rows we read
            #pragma unroll
            for (int i = 0; i < 16; i++) {
                int col = (i >> 2) * 256 + wave * 64 + (i & 3) * 16 + l16;
                out0[rb + col] = acc[i][q] * rn;       // f32 store
            }
        }
    }
}

// ---------------- launch ----------------
extern "C" void kernel_launch(void* const* d_in, const int* in_sizes, int n_in,
                              void* d_out, int out_size, void* d_ws, size_t ws_size,
                              hipStream_t stream) {
    const float* x   = (const float*)d_in[0];
    const float* lg  = (const float*)d_in[1];
    const float* W1  = (const float*)d_in[2];
    const float* W2  = (const float*)d_in[3];
    const float* gam = (const float*)d_in[4];
    const float* bet = (const float*)d_in[5];
    float* out0 = (float*)d_out;                       // f32 outputs (round-7 fix)
    float* out1 = out0 + (size_t)BSAMP * D_OUT;

    // ws: 33 KB of control ints only
    int* counts = (int*)d_ws;          // 16
    int* offs   = counts + 16;         // 16 (uses [0..10])
    int* cursor = offs + 16;           // 16
    int* cls    = cursor + 16;         // 4096
    int* idx    = cls + BSAMP;         // 4096

    k3_init<<<1, 64, 0, stream>>>(counts, cursor);
    k3_router<<<16, 256, 0, stream>>>(lg, cls, counts, out1);
    k3_scan<<<1, 64, 0, stream>>>(counts, offs, cursor);
    k3_scatter<<<16, 256, 0, stream>>>(cls, cursor, idx);

    dim3 g1(8, 64, NEXP);    // n-tiles x m-tiles (early-exit) x experts
    k3_gemm1<<<g1, 256, 0, stream>>>(x, W1, offs, idx, out0);

    dim3 g2(1, 256, NEXP);   // 16-row tiles (early-exit) x experts
    k3_gemm2<<<g2, 256, 0, stream>>>(W2, gam, bet, offs, idx, out0);
}

// Round 9
// 284.999 us; speedup vs baseline: 1.4380x; 1.4380x over previous
//
#include <hip/hip_runtime.h>
#include <math.h>

#define BSAMP 4096
#define D_IN  768
#define D_OUT 1024
#define NEXP  10
#define LN_EPS 1e-5f

typedef __attribute__((ext_vector_type(8))) short bf16x8;
typedef __attribute__((ext_vector_type(4))) float f32x4;

__device__ __forceinline__ float b2f(unsigned short u) {
    union { unsigned int i; float f; } v; v.i = ((unsigned int)u) << 16; return v.f;
}
__device__ __forceinline__ unsigned short f2b(float f) {
    union { float f; unsigned int i; } v; v.f = f;
    unsigned int x = v.i;
    unsigned int r = (x + 0x7fffu + ((x >> 16) & 1u)) >> 16;   // RNE
    return (unsigned short)r;
}

// ---------------- routing ----------------

__global__ void k4_init(int* counts, int* cursor) {
    int t = threadIdx.x;
    if (t < 16) { counts[t] = 0; cursor[t] = 0; }
}

__global__ void k4_router(const float* __restrict__ logits,
                          int* __restrict__ cls, int* __restrict__ counts,
                          float* __restrict__ out1) {
    int b = blockIdx.x * 256 + threadIdx.x;
    if (b >= BSAMP) return;
    const float* L = logits + (size_t)b * NEXP;
    float best = L[0]; int be = 0;
    #pragma unroll
    for (int e = 0; e < NEXP; e++) {
        float v = L[e];
        out1[(size_t)b * NEXP + e] = v;          // f32 bit-exact passthrough
        if (v > best) { best = v; be = e; }      // strict > == first-max (jnp.argmax)
    }
    cls[b] = be;
    atomicAdd(&counts[be], 1);
}

__global__ void k4_scan(const int* counts, int* offs, int* cursor) {
    if (threadIdx.x == 0) {
        int s = 0;
        for (int e = 0; e < NEXP; e++) { offs[e] = s; cursor[e] = s; s += counts[e]; }
        offs[NEXP] = s;
    }
}

__global__ void k4_scatter(const int* __restrict__ cls, int* __restrict__ cursor,
                           int* __restrict__ idx) {
    int b = blockIdx.x * 256 + threadIdx.x;
    if (b >= BSAMP) return;
    int p = atomicAdd(&cursor[cls[b]], 1);
    idx[p] = b;
}

// ---------------- weight convert+transpose: W[e][k][n] f32 -> tiled bf16 ----------------
// Wt tile layout: [e][nt(=n>>7)][kt(=k>>5)][nn(128)][kk(32)], tile = 4096 elems = 8 KB.
// Reads n-coalesced (256B/wave-instr), writes 64B contiguous per thread.
__global__ __launch_bounds__(256)
void k4_cvt(const float* __restrict__ W, unsigned short* __restrict__ Wt, int K) {
    const int t  = threadIdx.x;
    const int kt = blockIdx.x;          // K/32
    const int e  = blockIdx.z;
    const int n  = blockIdx.y * 256 + t;
    const int KT = K >> 5;
    const float* src = W + ((size_t)e * K + (size_t)kt * 32) * D_OUT + n;
    unsigned short v[32];
    #pragma unroll
    for (int j = 0; j < 32; j++) v[j] = f2b(src[(size_t)j * D_OUT]);
    const int nt = n >> 7, nn = n & 127;
    unsigned short* dst = Wt + ((((size_t)e * 8 + nt) * KT + kt) << 12) + nn * 32;
    #pragma unroll
    for (int j = 0; j < 4; j++)
        *(bf16x8*)&dst[j * 8] = *(bf16x8*)&v[j * 8];
}

// ---------------- GEMM1: e1g[p][n] = bf16( x[idx[p]] @ W1[e] ), grouped rows ----------------
// 64x128 tile, BK=32. B via global_load_lds (flat copy of pre-tiled bf16).
__global__ __launch_bounds__(256)
void k4_gemm1(const float* __restrict__ X, const unsigned short* __restrict__ W1t,
              const int* __restrict__ offs, const int* __restrict__ idx,
              unsigned short* __restrict__ e1g) {
    const int e = blockIdx.z;
    const int rowStart = offs[e] + blockIdx.y * 64;
    const int rowEnd = offs[e + 1];
    if (rowStart >= rowEnd) return;
    const int nt = blockIdx.x;                   // 0..7
    const int n0 = nt * 128;

    __shared__ __align__(16) unsigned short Alds[64 * 32];   // 4 KB
    __shared__ __align__(16) unsigned short Blds[128 * 32];  // 8 KB
    __shared__ int rowIdxL[64];

    const int tid  = threadIdx.x;
    const int lane = tid & 63;
    const int wave = tid >> 6;
    const int quad = lane >> 4;
    const int l16  = lane & 15;

    if (tid < 64) {
        int p = rowStart + tid;
        int ps = p < rowEnd ? p : rowEnd - 1;
        rowIdxL[tid] = idx[ps];
    }
    __syncthreads();

    const int ar = tid >> 2;
    const int ak = (tid & 3) * 8;
    const float* aBase = X + (size_t)rowIdxL[ar] * D_IN;

    f32x4 acc[2][4];
    const f32x4 zf = {0.f, 0.f, 0.f, 0.f};
    #pragma unroll
    for (int r = 0; r < 2; r++)
        #pragma unroll
        for (int c = 0; c < 4; c++) acc[r][c] = zf;

    const int wrow = (wave & 1) * 32;
    const int wcol = (wave >> 1) * 64;

    for (int kt = 0; kt < D_IN / 32; kt++) {
        const unsigned short* tile = W1t + ((((size_t)e * 8 + nt) * (D_IN / 32) + kt) << 12);
        __syncthreads();
        // B: async flat copy, 2 x 16B per thread (dst byte offset == tid*16 per half)
        __builtin_amdgcn_global_load_lds(
            (const __attribute__((address_space(1))) unsigned int*)(tile + tid * 8),
            (__attribute__((address_space(3))) unsigned int*)&Blds[tid * 8], 16, 0, 0);
        __builtin_amdgcn_global_load_lds(
            (const __attribute__((address_space(1))) unsigned int*)(tile + 2048 + tid * 8),
            (__attribute__((address_space(3))) unsigned int*)&Blds[2048 + tid * 8], 16, 0, 0);
        {   // A: f32 -> bf16 -> LDS
            const float* s = aBase + kt * 32 + ak;
            float4 v0 = *(const float4*)s;
            float4 v1 = *(const float4*)(s + 4);
            unsigned short t[8] = { f2b(v0.x), f2b(v0.y), f2b(v0.z), f2b(v0.w),
                                    f2b(v1.x), f2b(v1.y), f2b(v1.z), f2b(v1.w) };
            *(bf16x8*)&Alds[ar * 32 + ak] = *(bf16x8*)t;
        }
        __syncthreads();
        bf16x8 a[2], bfr[4];
        #pragma unroll
        for (int r = 0; r < 2; r++)
            a[r] = *(const bf16x8*)&Alds[(wrow + r * 16 + l16) * 32 + quad * 8];
        #pragma unroll
        for (int c = 0; c < 4; c++)
            bfr[c] = *(const bf16x8*)&Blds[(wcol + c * 16 + l16) * 32 + quad * 8];
        #pragma unroll
        for (int r = 0; r < 2; r++)
            #pragma unroll
            for (int c = 0; c < 4; c++)
                acc[r][c] = __builtin_amdgcn_mfma_f32_16x16x32_bf16(a[r], bfr[c], acc[r][c], 0, 0, 0);
    }

    // C/D: col = lane&15, row = quad*4 + reg -> grouped bf16 store
    #pragma unroll
    for (int r = 0; r < 2; r++)
        #pragma unroll
        for (int c = 0; c < 4; c++)
            #pragma unroll
            for (int q = 0; q < 4; q++) {
                int m = wrow + r * 16 + quad * 4 + q;
                int pp = rowStart + m;
                if (pp < rowEnd) {
                    int n = n0 + wcol + c * 16 + l16;
                    e1g[(size_t)pp * D_OUT + n] = f2b(acc[r][c][q]);
                }
            }
}

// ---------------- GEMM2: out0[idx[p]][n] = f32( gelu(e1g)@W2 + e1g ) ----------------
__global__ __launch_bounds__(256)
void k4_gemm2(const unsigned short* __restrict__ e1g, const unsigned short* __restrict__ W2t,
              const int* __restrict__ offs, const int* __restrict__ idx,
              float* __restrict__ out0) {
    const int e = blockIdx.z;
    const int rowStart = offs[e] + blockIdx.y * 64;
    const int rowEnd = offs[e + 1];
    if (rowStart >= rowEnd) return;
    const int nt = blockIdx.x;
    const int n0 = nt * 128;

    __shared__ __align__(16) unsigned short Alds[64 * 32];
    __shared__ __align__(16) unsigned short Blds[128 * 32];
    __shared__ int rowIdxL[64];

    const int tid  = threadIdx.x;
    const int lane = tid & 63;
    const int wave = tid >> 6;
    const int quad = lane >> 4;
    const int l16  = lane & 15;

    if (tid < 64) {
        int p = rowStart + tid;
        int ps = p < rowEnd ? p : rowEnd - 1;
        rowIdxL[tid] = idx[ps];
    }
    __syncthreads();

    const int ar = tid >> 2;
    const int ak = (tid & 3) * 8;
    int ap = rowStart + ar;
    const unsigned short* aBase = e1g + (size_t)(ap < rowEnd ? ap : rowEnd - 1) * D_OUT;

    f32x4 acc[2][4];
    const f32x4 zf = {0.f, 0.f, 0.f, 0.f};
    #pragma unroll
    for (int r = 0; r < 2; r++)
        #pragma unroll
        for (int c = 0; c < 4; c++) acc[r][c] = zf;

    const int wrow = (wave & 1) * 32;
    const int wcol = (wave >> 1) * 64;

    for (int kt = 0; kt < D_OUT / 32; kt++) {
        const unsigned short* tile = W2t + ((((size_t)e * 8 + nt) * (D_OUT / 32) + kt) << 12);
        __syncthreads();
        __builtin_amdgcn_global_load_lds(
            (const __attribute__((address_space(1))) unsigned int*)(tile + tid * 8),
            (__attribute__((address_space(3))) unsigned int*)&Blds[tid * 8], 16, 0, 0);
        __builtin_amdgcn_global_load_lds(
            (const __attribute__((address_space(1))) unsigned int*)(tile + 2048 + tid * 8),
            (__attribute__((address_space(3))) unsigned int*)&Blds[2048 + tid * 8], 16, 0, 0);
        {   // A: gelu(e1g) -> bf16 -> LDS
            bf16x8 av = *(const bf16x8*)(aBase + kt * 32 + ak);
            const unsigned short* avp = (const unsigned short*)&av;
            unsigned short t[8];
            #pragma unroll
            for (int j = 0; j < 8; j++) {
                float v = b2f(avp[j]);
                t[j] = f2b(v / (1.0f + __expf(-1.702f * v)));
            }
            *(bf16x8*)&Alds[ar * 32 + ak] = *(bf16x8*)t;
        }
        __syncthreads();
        bf16x8 a[2], bfr[4];
        #pragma unroll
        for (int r = 0; r < 2; r++)
            a[r] = *(const bf16x8*)&Alds[(wrow + r * 16 + l16) * 32 + quad * 8];
        #pragma unroll
        for (int c = 0; c < 4; c++)
            bfr[c] = *(const bf16x8*)&Blds[(wcol + c * 16 + l16) * 32 + quad * 8];
        #pragma unroll
        for (int r = 0; r < 2; r++)
            #pragma unroll
            for (int c = 0; c < 4; c++)
                acc[r][c] = __builtin_amdgcn_mfma_f32_16x16x32_bf16(a[r], bfr[c], acc[r][c], 0, 0, 0);
    }

    // epilogue: s = acc + e1, scatter f32 to out0 original rows
    #pragma unroll
    for (int r = 0; r < 2; r++)
        #pragma unroll
        for (int c = 0; c < 4; c++)
            #pragma unroll
            for (int q = 0; q < 4; q++) {
                int m = wrow + r * 16 + quad * 4 + q;
                int pp = rowStart + m;
                if (pp < rowEnd) {
                    int n = n0 + wcol + c * 16 + l16;
                    float s = acc[r][c][q] + b2f(e1g[(size_t)pp * D_OUT + n]);
                    out0[(size_t)rowIdxL[m] * D_OUT + n] = s;
                }
            }
}

// ---------------- LN + L2, in place on out0; one wave per row ----------------
__global__ __launch_bounds__(256)
void k4_ln(float* __restrict__ out0, const int* __restrict__ cls,
           const float* __restrict__ gam, const float* __restrict__ bet) {
    const int wave = threadIdx.x >> 6;
    const int lane = threadIdx.x & 63;
    const int b = blockIdx.x * 4 + wave;
    const int e = cls[b];

    float* row = out0 + (size_t)b * D_OUT + lane * 16;
    float v[16];
    #pragma unroll
    for (int j = 0; j < 4; j++) {
        float4 t = *(const float4*)(row + j * 4);
        v[j*4] = t.x; v[j*4+1] = t.y; v[j*4+2] = t.z; v[j*4+3] = t.w;
    }

    float sum = 0.f, sq = 0.f;
    #pragma unroll
    for (int j = 0; j < 16; j++) { sum += v[j]; sq += v[j] * v[j]; }
    #pragma unroll
    for (int o = 32; o; o >>= 1) { sum += __shfl_xor(sum, o, 64); sq += __shfl_xor(sq, o, 64); }
    float mean = sum * (1.0f / 1024.0f);
    float var = sq * (1.0f / 1024.0f) - mean * mean;
    float inv = rsqrtf(var + LN_EPS);

    const float* gp = gam + (size_t)e * D_OUT + lane * 16;
    const float* bp = bet + (size_t)e * D_OUT + lane * 16;
    float y[16]; float y2 = 0.f;
    #pragma unroll
    for (int j = 0; j < 16; j++) {
        y[j] = (v[j] - mean) * inv * gp[j] + bp[j];
        y2 += y[j] * y[j];
    }
    #pragma unroll
    for (int o = 32; o; o >>= 1) y2 += __shfl_xor(y2, o, 64);
    float rn = rsqrtf(y2);

    #pragma unroll
    for (int j = 0; j < 4; j++) {
        float4 t = { y[j*4] * rn, y[j*4+1] * rn, y[j*4+2] * rn, y[j*4+3] * rn };
        *(float4*)(row + j * 4) = t;
    }
}

// ---------------- launch ----------------
extern "C" void kernel_launch(void* const* d_in, const int* in_sizes, int n_in,
                              void* d_out, int out_size, void* d_ws, size_t ws_size,
                              hipStream_t stream) {
    const float* x   = (const float*)d_in[0];
    const float* lg  = (const float*)d_in[1];
    const float* W1  = (const float*)d_in[2];
    const float* W2  = (const float*)d_in[3];
    const float* gam = (const float*)d_in[4];
    const float* bet = (const float*)d_in[5];
    float* out0 = (float*)d_out;
    float* out1 = out0 + (size_t)BSAMP * D_OUT;

    // ws layout: [0,64K) control | [64K, 64K+21M) Wt (W1t then W2t, sequential reuse)
    //            | [64K+21M, +8M) e1g grouped bf16.  Total ~30.5 MB.
    char* ws = (char*)d_ws;
    int* counts = (int*)ws;            // 16
    int* offs   = counts + 16;         // 16
    int* cursor = offs + 16;           // 16
    int* cls    = cursor + 16;         // 4096
    int* idx    = cls + BSAMP;         // 4096
    unsigned short* Wt  = (unsigned short*)(ws + 65536);
    unsigned short* e1g = (unsigned short*)(ws + 65536 + 22020096);  // 21 MB after Wt

    k4_init<<<1, 64, 0, stream>>>(counts, cursor);
    k4_router<<<16, 256, 0, stream>>>(lg, cls, counts, out1);
    k4_scan<<<1, 64, 0, stream>>>(counts, offs, cursor);
    k4_scatter<<<16, 256, 0, stream>>>(cls, cursor, idx);

    // W1 -> tiled bf16, then GEMM1
    dim3 gc1(D_IN / 32, 4, NEXP);
    k4_cvt<<<gc1, 256, 0, stream>>>(W1, Wt, D_IN);
    dim3 g1(8, 64, NEXP);
    k4_gemm1<<<g1, 256, 0, stream>>>(x, Wt, offs, idx, e1g);

    // W2 -> tiled bf16 (reuses Wt region; stream-ordered after gemm1), then GEMM2
    dim3 gc2(D_OUT / 32, 4, NEXP);
    k4_cvt<<<gc2, 256, 0, stream>>>(W2, Wt, D_OUT);
    dim3 g2(8, 64, NEXP);
    k4_gemm2<<<g2, 256, 0, stream>>>(e1g, Wt, offs, idx, out0);

    k4_ln<<<BSAMP / 4, 256, 0, stream>>>(out0, cls, gam, bet);
}